// Round 12
// baseline (160.415 us; speedup 1.0000x reference)
//
#include <hip/hip_runtime.h>

typedef __attribute__((ext_vector_type(8))) short s16x8;
typedef __attribute__((ext_vector_type(4))) float f32x4;
typedef __attribute__((ext_vector_type(16))) float f32x16;
typedef unsigned short u16;
typedef unsigned int u32;
typedef unsigned long long u64;

// ---------- helpers ----------
__device__ __forceinline__ u16 f2bf(float f) {            // RNE f32 -> bf16
  u32 u = __builtin_bit_cast(u32, f);
  u += 0x7fff + ((u >> 16) & 1);
  return (u16)(u >> 16);
}

__device__ __forceinline__ float exp2fast(float x) {
#if __has_builtin(__builtin_amdgcn_exp2f)
  return __builtin_amdgcn_exp2f(x);
#else
  return __expf(x * 0.6931471805599453f);
#endif
}

__device__ __forceinline__ void gload16(const void* g, void* l) {
  __builtin_amdgcn_global_load_lds((const __attribute__((address_space(1))) u32*)g,
                                   (__attribute__((address_space(3))) u32*)l, 16, 0, 0);
}

#define MFMA(a, b, c) __builtin_amdgcn_mfma_f32_16x16x32_bf16((a), (b), (c), 0, 0, 0)
#define MFMA32(a, b, c) __builtin_amdgcn_mfma_f32_32x32x16_bf16((a), (b), (c), 0, 0, 0)

// scale * log2(e), folded into Q at projection time
#define QSCALE 0.18033688011112042f

// ---------- prologue: cvt x3 | transpose x4 (mask moved into proj) ----------
__global__ __launch_bounds__(256) void prep(
    const float* __restrict__ q, const float* __restrict__ k, const float* __restrict__ v,
    u16* __restrict__ oq, u16* __restrict__ ok, u16* __restrict__ ov,
    const float* __restrict__ W0, const float* __restrict__ W1,
    const float* __restrict__ W2, const float* __restrict__ W3,
    u16* __restrict__ T0, u16* __restrict__ T1, u16* __restrict__ T2, u16* __restrict__ T3) {
  __shared__ float t[32][33];
  const int bx = blockIdx.x, tid = threadIdx.x;
  if (bx < 6144) {                               // fp32 -> bf16, 8 elems/thread
    int z = bx >> 11;
    const float* src = (z == 0) ? q : (z == 1) ? k : v;
    u16* dst = (z == 0) ? oq : (z == 1) ? ok : ov;
    int i = (bx & 2047) * 256 + tid;
    const float4* s4 = (const float4*)src;
    float4 a = s4[2 * i], bb = s4[2 * i + 1];
    uint4 o;
    o.x = (u32)f2bf(a.x) | ((u32)f2bf(a.y) << 16);
    o.y = (u32)f2bf(a.z) | ((u32)f2bf(a.w) << 16);
    o.z = (u32)f2bf(bb.x) | ((u32)f2bf(bb.y) << 16);
    o.w = (u32)f2bf(bb.z) | ((u32)f2bf(bb.w) << 16);
    ((uint4*)dst)[i] = o;
  } else {                                       // W [1024][1024] f32 -> WT bf16
    int r = bx - 6144;
    int z = r >> 10, t2 = r & 1023;
    const float* W = (z == 0) ? W0 : (z == 1) ? W1 : (z == 2) ? W2 : W3;
    u16* WT = (z == 0) ? T0 : (z == 1) ? T1 : (z == 2) ? T2 : T3;
    int nb = t2 & 31, kb = t2 >> 5;
    int tx = tid & 31, ty = tid >> 5;
    int n = nb * 32 + tx;
#pragma unroll
    for (int j = 0; j < 4; j++) {
      int kk = kb * 32 + ty + 8 * j;
      t[ty + 8 * j][tx] = W[(size_t)kk * 1024 + n];
    }
    __syncthreads();
    int kk = kb * 32 + tx;
#pragma unroll
    for (int j = 0; j < 4; j++) {
      int n2 = nb * 32 + ty + 8 * j;
      WT[(size_t)n2 * 1024 + kk] = f2bf(t[tx][ty + 8 * j]);
    }
  }
}

// ---------- pipelined GEMM core (dist-2 dbuf, counted vmcnt, chunk swizzle) ----------
template <int BM, int BN>
__device__ __forceinline__ void gemm_core(const u16* __restrict__ A, const u16* __restrict__ BT,
                                          int m0, int n0, u16* Ash, u16* Bsh,
                                          f32x4 (&acc)[BM / 32][BN / 32]) {
  constexpr int MF = BM / 32, NF = BN / 32;
  constexpr int BATCH = BM / 32 + BN / 32;   // gload16 per thread per K-tile
  const int tid = threadIdx.x;
  const int lane = tid & 63, wid = tid >> 6;
  const int r16 = lane & 15, g = lane >> 4;
  const int wm = wid >> 1, wn = wid & 1;
  const int swz = r16 & 7;
  const f32x4 vz = {0.f, 0.f, 0.f, 0.f};
#pragma unroll
  for (int mf = 0; mf < MF; mf++)
#pragma unroll
    for (int nf = 0; nf < NF; nf++) acc[mf][nf] = vz;

  auto stage = [&](int buf, int k0) {
#pragma unroll
    for (int i = 0; i < MF; i++) {
      int ch = i * 256 + tid;
      int row = ch >> 3, sc = (ch & 7) ^ (row & 7);
      gload16(A + (((size_t)(m0 + row)) << 10) + k0 + sc * 8,
              Ash + (size_t)buf * (BM * 64) + ch * 8);
    }
#pragma unroll
    for (int i = 0; i < NF; i++) {
      int ch = i * 256 + tid;
      int row = ch >> 3, sc = (ch & 7) ^ (row & 7);
      gload16(BT + (((size_t)(n0 + row)) << 10) + k0 + sc * 8,
              Bsh + (size_t)buf * (BN * 64) + ch * 8);
    }
  };

  asm volatile("" ::: "memory");
  stage(0, 0);
  asm volatile("" ::: "memory");
  stage(1, 64);
  asm volatile("" ::: "memory");

  for (int t = 0; t < 16; t++) {
    const int cur = t & 1;
    if (t == 15) {
      asm volatile("s_waitcnt vmcnt(0)" ::: "memory");
    } else if constexpr (BATCH == 8) {
      asm volatile("s_waitcnt vmcnt(8)" ::: "memory");
    } else {
      asm volatile("s_waitcnt vmcnt(6)" ::: "memory");
    }
    asm volatile("s_barrier" ::: "memory");      // buf(cur) ready

    const u16* Acur = Ash + (size_t)cur * (BM * 64);
    const u16* Bcur = Bsh + (size_t)cur * (BN * 64);
    __builtin_amdgcn_s_setprio(1);
#pragma unroll
    for (int kk = 0; kk < 2; kk++) {
      const int c = (kk * 4 + g);
      s16x8 af[MF], bfr[NF];
#pragma unroll
      for (int mf = 0; mf < MF; mf++)
        af[mf] = *(const s16x8*)(Acur + ((wm * (BM / 2) + mf * 16 + r16) << 6) +
                                 ((c ^ swz) << 3));
#pragma unroll
      for (int nf = 0; nf < NF; nf++)
        bfr[nf] = *(const s16x8*)(Bcur + ((wn * (BN / 2) + nf * 16 + r16) << 6) +
                                  ((c ^ swz) << 3));
#pragma unroll
      for (int mf = 0; mf < MF; mf++)
#pragma unroll
        for (int nf = 0; nf < NF; nf++) acc[mf][nf] = MFMA(af[mf], bfr[nf], acc[mf][nf]);
    }
    __builtin_amdgcn_s_setprio(0);

    asm volatile("s_barrier" ::: "memory");      // all waves done reading buf(cur)
    if (t + 2 < 16) stage(cur, (t + 2) * 64);    // refill freed buffer
  }
}

// ---------- fused QKV projection + mask bitpack ----------
// z=0 Q (pre-scaled), z=1 K, z=2 V (transposed), z=3 mask->bitmask (transposed,
// HBM-streaming; overlaps proj's compute-bound tail)
__global__ __launch_bounds__(256, 2) void proj_gemm(
    const u16* __restrict__ Xq, const u16* __restrict__ Xk, const u16* __restrict__ Xv,
    const u16* __restrict__ WqT, const u16* __restrict__ WkT, const u16* __restrict__ WvT,
    const float* __restrict__ bq, const float* __restrict__ bk, const float* __restrict__ bv,
    u16* __restrict__ Qo, u16* __restrict__ Ko, u16* __restrict__ Vto,
    const int* __restrict__ mask, u64* __restrict__ mb) {
  __shared__ u16 Ash[2 * 128 * 64], Bsh[2 * 128 * 64];
  const int z = blockIdx.z;
  if (z == 3) {                                  // mask role: 256 blocks, grid-stride
    int m = blockIdx.y * 8 + blockIdx.x;         // [0,256)
    int w = threadIdx.x >> 6, lane = threadIdx.x & 63;
#pragma unroll 4
    for (int j = 0; j < 128; j++) {
      int wi = (m * 4 + w) * 128 + j;            // u64 word index, [0,131072)
      u64 bits = __ballot(mask[((size_t)wi << 6) + lane] != 0);
      if (lane == 0) {
        int b_ = wi >> 16, q_ = (wi >> 5) & 2047, t_ = wi & 31;
        mb[((size_t)b_ << 16) + ((size_t)t_ << 11) + q_] = bits;   // [b][word][q]
      }
    }
    return;
  }
  const u16* A = (z == 0) ? Xq : (z == 1) ? Xk : Xv;
  const u16* BT = (z == 0) ? WqT : (z == 1) ? WkT : WvT;
  const float* bias = (z == 0) ? bq : (z == 1) ? bk : bv;
  u16* O = (z == 0) ? Qo : (z == 1) ? Ko : Vto;
  const float sc = (z == 0) ? QSCALE : 1.0f;
  const int m0 = blockIdx.y * 128, n0 = blockIdx.x * 128;
  f32x4 acc[4][4];
  gemm_core<128, 128>(A, BT, m0, n0, Ash, Bsh, acc);
  const int tid = threadIdx.x, lane = tid & 63, wid = tid >> 6;
  const int r16 = lane & 15, g = lane >> 4, wm = wid >> 1, wn = wid & 1;
#pragma unroll
  for (int nf = 0; nf < 4; nf++) {
    int col = n0 + wn * 64 + nf * 16 + r16;
    float bb = bias[col];
    int h = col >> 6, d = col & 63;
#pragma unroll
    for (int mf = 0; mf < 4; mf++) {
#pragma unroll
      for (int ri = 0; ri < 4; ri++) {
        int row = m0 + wm * 64 + mf * 16 + g * 4 + ri;
        int b_ = row >> 11, s_ = row & 2047;
        u16 val = f2bf((acc[mf][nf][ri] + bb) * sc);
        if (z < 2)
          O[((((size_t)b_ * 16 + h) * 2048 + s_) << 6) + d] = val;     // [B,H,S,64]
        else
          O[((((size_t)b_ * 16 + h) * 64 + d) << 11) + s_] = val;     // [B,H,64,S]
      }
    }
  }
}

// ---------- output projection: out = ctx @ WoT^T + bo (fp32) ----------
__global__ __launch_bounds__(256, 2) void out_gemm(const u16* __restrict__ ctx,
                                                   const u16* __restrict__ WoT,
                                                   const float* __restrict__ bo,
                                                   float* __restrict__ out) {
  __shared__ u16 Ash[2 * 64 * 64], Bsh[2 * 128 * 64];
  const int m0 = blockIdx.y * 64, n0 = blockIdx.x * 128;
  f32x4 acc[2][4];
  gemm_core<64, 128>(ctx, WoT, m0, n0, Ash, Bsh, acc);
  const int tid = threadIdx.x, lane = tid & 63, wid = tid >> 6;
  const int r16 = lane & 15, g = lane >> 4, wm = wid >> 1, wn = wid & 1;
#pragma unroll
  for (int nf = 0; nf < 4; nf++) {
    int col = n0 + wn * 64 + nf * 16 + r16;
    float bb = bo[col];
#pragma unroll
    for (int mf = 0; mf < 2; mf++) {
#pragma unroll
      for (int ri = 0; ri < 4; ri++) {
        int row = m0 + wm * 32 + mf * 16 + g * 4 + ri;
        out[((size_t)row << 10) + col] = acc[mf][nf][ri] + bb;
      }
    }
  }
}

// ---------- softmax + in-register P->A-frag pack (32x32 C layout) ----------
__device__ __forceinline__ s16x8 pack4u(u32 a0, u32 a1, u32 b0, u32 b1) {
  union { u32 u[4]; s16x8 v; } p;
  p.u[0] = a0; p.u[1] = a1; p.u[2] = b0; p.u[3] = b1;
  return p.v;
}

__device__ __forceinline__ void softpack(const f32x16& sv, u32 wm, s16x8& pA, s16x8& pB) {
  float e[16];
#pragma unroll
  for (int qd = 0; qd < 4; qd++)
#pragma unroll
    for (int j = 0; j < 4; j++) {
      const int bit = qd * 8 + j;
      float ex = exp2fast(sv[qd * 4 + j]);
      u32 sext = (u32)(((int)(wm << (31 - bit))) >> 31);   // all-ones / zero
      e[qd * 4 + j] = __builtin_bit_cast(float, __builtin_bit_cast(u32, ex) & sext);
    }
#pragma unroll
  for (int n = 0; n < 2; n++) {
    u32 a0, a1, b0, b1;
    asm("v_cvt_pk_bf16_f32 %0, %1, %2" : "=v"(a0) : "v"(e[n * 8 + 0]), "v"(e[n * 8 + 1]));
    asm("v_cvt_pk_bf16_f32 %0, %1, %2" : "=v"(a1) : "v"(e[n * 8 + 2]), "v"(e[n * 8 + 3]));
    asm("v_cvt_pk_bf16_f32 %0, %1, %2" : "=v"(b0) : "v"(e[n * 8 + 4]), "v"(e[n * 8 + 5]));
    asm("v_cvt_pk_bf16_f32 %0, %1, %2" : "=v"(b1) : "v"(e[n * 8 + 6]), "v"(e[n * 8 + 7]));
    asm("v_permlane32_swap_b32 %0, %1" : "+v"(a0), "+v"(b0));
    asm("v_permlane32_swap_b32 %0, %1" : "+v"(a1), "+v"(b1));
    if (n == 0) pA = pack4u(a0, a1, b0, b1);
    else        pB = pack4u(a0, a1, b0, b1);
  }
}

// ---------- flash attention v11 (= v9 + transposed coalesced mask loads) ----------
// block = 4 waves x 32 q = 128 q. 4 sub-buffers of 64 kv, dist-2 iterations,
// counted vmcnt(10), 2 barriers per 128 kv. Row-sum via ones-MFMA.
__global__ __launch_bounds__(256, 2) void flash_attn(const u16* __restrict__ Q,
                                                     const u16* __restrict__ K,
                                                     const u16* __restrict__ Vt,
                                                     const u64* __restrict__ Mb64,
                                                     u16* __restrict__ ctx) {
  __shared__ __align__(16) u16 Ksh[4][64][64];  // [sub-buf][kv][d]  chunk-swizzled
  __shared__ __align__(16) u16 Vsh[4][64][64];  // [sub-buf][d][kv]  chunk-swizzled

  const int tid = threadIdx.x, w = tid >> 6, lane = tid & 63;
  const int l31 = lane & 31, h5 = lane >> 5, l7 = lane & 7;

  // XCD-chunked swizzle: all 16 q-tiles of one (b,h) land on one XCD's L2
  int work = ((int)blockIdx.x & 7) * 64 + ((int)blockIdx.x >> 3);
  const int qt = work & 15, bh = work >> 4;     // bh = b*16+h
  const int b = bh >> 4, h = bh & 15;
  const int q0 = qt * 128 + w * 32;             // wave's 32 q rows

  const u16* Qb = Q + ((size_t)bh << 17);
  const u16* Kb = K + ((size_t)bh << 17);
  const u16* Vb = Vt + ((size_t)bh << 17);
  const u64* MrowT = Mb64 + ((size_t)b << 16) + (q0 + l31);  // transposed [b][word][q]

  const int srow = tid >> 3, sk16 = tid & 7;
#define STAGE(buf, kv0)                                                                   \
  {                                                                                       \
    _Pragma("unroll") for (int i = 0; i < 2; i++) {                                       \
      int row = i * 32 + srow;                                                            \
      int sc = sk16 ^ (row & 7);                                                          \
      gload16(Kb + (((size_t)((kv0) + row)) << 6) + sc * 8,                               \
              (char*)&Ksh[buf][0][0] + (i * 256 + tid) * 16);                             \
      gload16(Vb + (((size_t)row) << 11) + (kv0) + sc * 8,                                \
              (char*)&Vsh[buf][0][0] + (i * 256 + tid) * 16);                             \
    }                                                                                     \
  }

  // Q as B-fragment (pre-scaled): lane holds Q[q0+l31][dk*16 + h5*8 .. +7]
  s16x8 aq[4];
#pragma unroll
  for (int dk = 0; dk < 4; dk++)
    aq[dk] = *(const s16x8*)(Qb + ((q0 + l31) << 6) + dk * 16 + h5 * 8);
  asm volatile("" ::: "memory");   // pin: aq loads before batch0
  STAGE(0, 0);
  STAGE(1, 64);
  u64 m_c0 = MrowT[0], m_c1 = MrowT[(size_t)1 << 11];   // batch0: 8 gload + 2 mask
  asm volatile("" ::: "memory");
  STAGE(2, 128);
  STAGE(3, 192);
  u64 m_n0 = MrowT[(size_t)2 << 11], m_n1 = MrowT[(size_t)3 << 11];   // batch1
  asm volatile("" ::: "memory");

  s16x8 vones;
#pragma unroll
  for (int j = 0; j < 8; j++) vones[j] = (short)0x3F80;  // bf16 1.0

  f32x16 o0, o1, o4;
#pragma unroll
  for (int r = 0; r < 16; r++) { o0[r] = 0.f; o1[r] = 0.f; o4[r] = 0.f; }

  for (int t = 0; t < 16; t++) {            // 128 kv per iteration
    const int base = (t & 1) * 2;
    if (t == 15) {
      asm volatile("s_waitcnt vmcnt(0)" ::: "memory");
    } else {
      asm volatile("s_waitcnt vmcnt(10)" ::: "memory");
    }
    asm volatile("s_barrier" ::: "memory");          // sub-bufs base, base+1 ready

    const u16* KcA = &Ksh[base][0][0];
    const u16* KcB = &Ksh[base + 1][0][0];
    const u16* VcA = &Vsh[base][0][0];
    const u16* VcB = &Vsh[base + 1][0][0];

    // QK^T (32x32x16) for both 64-kv halves: 4 independent chains
    f32x16 s0, s1, s2, s3;
#pragma unroll
    for (int r = 0; r < 16; r++) { s0[r] = 0.f; s1[r] = 0.f; s2[r] = 0.f; s3[r] = 0.f; }
    __builtin_amdgcn_s_setprio(1);
#pragma unroll
    for (int dk = 0; dk < 4; dk++) {
      int ch = (((dk << 1) + h5) ^ l7) << 3;
      s16x8 akA0 = *(const s16x8*)(KcA + (l31 << 6) + ch);
      s16x8 akA1 = *(const s16x8*)(KcA + ((32 + l31) << 6) + ch);
      s16x8 akB0 = *(const s16x8*)(KcB + (l31 << 6) + ch);
      s16x8 akB1 = *(const s16x8*)(KcB + ((32 + l31) << 6) + ch);
      s0 = MFMA32(akA0, aq[dk], s0);
      s1 = MFMA32(akA1, aq[dk], s1);
      s2 = MFMA32(akB0, aq[dk], s2);
      s3 = MFMA32(akB1, aq[dk], s3);
    }
    __builtin_amdgcn_s_setprio(0);

    // half A: softmax+pack then PV (+ ones-MFMA row-sum)
    u64 mshA = m_c0 >> (h5 << 2);
    s16x8 pa[4];
    softpack(s0, (u32)mshA, pa[0], pa[1]);
    softpack(s1, (u32)(mshA >> 32), pa[2], pa[3]);
    __builtin_amdgcn_s_setprio(1);
#pragma unroll
    for (int km = 0; km < 4; km++) {
      int ch = (((km << 1) + h5) ^ l7) << 3;
      s16x8 bv0 = *(const s16x8*)(VcA + (l31 << 6) + ch);
      s16x8 bv1 = *(const s16x8*)(VcA + ((32 + l31) << 6) + ch);
      o0 = MFMA32(pa[km], bv0, o0);
      o1 = MFMA32(pa[km], bv1, o1);
      o4 = MFMA32(pa[km], vones, o4);
    }
    __builtin_amdgcn_s_setprio(0);

    // half B
    u64 mshB = m_c1 >> (h5 << 2);
    s16x8 pb[4];
    softpack(s2, (u32)mshB, pb[0], pb[1]);
    softpack(s3, (u32)(mshB >> 32), pb[2], pb[3]);
    __builtin_amdgcn_s_setprio(1);
#pragma unroll
    for (int km = 0; km < 4; km++) {
      int ch = (((km << 1) + h5) ^ l7) << 3;
      s16x8 bv0 = *(const s16x8*)(VcB + (l31 << 6) + ch);
      s16x8 bv1 = *(const s16x8*)(VcB + ((32 + l31) << 6) + ch);
      o0 = MFMA32(pb[km], bv0, o0);
      o1 = MFMA32(pb[km], bv1, o1);
      o4 = MFMA32(pb[km], vones, o4);
    }
    __builtin_amdgcn_s_setprio(0);

    asm volatile("s_barrier" ::: "memory");      // all waves done reading base, base+1
    u64 mw0 = 0, mw1 = 0;
    if (t + 2 < 16) {                            // restage freed sub-buffers (dist-2)
      STAGE(base, (2 * t + 4) * 64);
      STAGE(base + 1, (2 * t + 5) * 64);
      mw0 = MrowT[(size_t)(2 * t + 4) << 11];
      mw1 = MrowT[(size_t)(2 * t + 5) << 11];
    }
    m_c0 = m_n0; m_c1 = m_n1;
    m_n0 = mw0;  m_n1 = mw1;
  }
#undef STAGE

  // o4[r] = rowsum for q = q0 + (r&3)+8*(r>>2)+4*h5 -> normalize + write ctx bf16
#pragma unroll
  for (int r = 0; r < 16; r++) {
    int qr = (r & 3) + 8 * (r >> 2) + 4 * h5;
    size_t rowoff = ((size_t)((b << 11) + q0 + qr)) << 10;
    float iv = 1.f / o4[r];
    ctx[rowoff + (h << 6) + l31]      = f2bf(o0[r] * iv);
    ctx[rowoff + (h << 6) + 32 + l31] = f2bf(o1[r] * iv);
  }
}

// ---------- host ----------
extern "C" void kernel_launch(void* const* d_in, const int* in_sizes, int n_in,
                              void* d_out, int out_size, void* d_ws, size_t ws_size,
                              hipStream_t stream) {
  const float* query = (const float*)d_in[0];
  const float* key_  = (const float*)d_in[1];
  const float* value = (const float*)d_in[2];
  const int*   mask  = (const int*)d_in[3];
  const float* Wq = (const float*)d_in[4];
  const float* bq = (const float*)d_in[5];
  const float* Wk = (const float*)d_in[6];
  const float* bk = (const float*)d_in[7];
  const float* Wv = (const float*)d_in[8];
  const float* bv = (const float*)d_in[9];
  const float* Wo = (const float*)d_in[10];
  const float* bo = (const float*)d_in[11];

  const size_t MB = 1048576;
  char* ws = (char*)d_ws;
  u16* Xq  = (u16*)(ws + 0 * MB);
  u16* Xk  = (u16*)(ws + 8 * MB);
  u16* Xv  = (u16*)(ws + 16 * MB);
  u16* WqT = (u16*)(ws + 24 * MB);
  u16* WkT = (u16*)(ws + 26 * MB);
  u16* WvT = (u16*)(ws + 28 * MB);
  u16* WoT = (u16*)(ws + 30 * MB);
  u16* Qd  = (u16*)(ws + 32 * MB);
  u16* Kd  = (u16*)(ws + 40 * MB);
  u16* Vtd = (u16*)(ws + 48 * MB);
  u16* ctx = (u16*)(ws + 56 * MB);
  u64* Mb  = (u64*)(ws + 72 * MB);   // 1 MB bitmask (transposed [b][word][q])

  prep<<<10240, 256, 0, stream>>>(query, key_, value, Xq, Xk, Xv,
                                  Wq, Wk, Wv, Wo, WqT, WkT, WvT, WoT);

  proj_gemm<<<dim3(8, 32, 4), 256, 0, stream>>>(Xq, Xk, Xv, WqT, WkT, WvT, bq, bk, bv,
                                                Qd, Kd, Vtd, mask, Mb);
  flash_attn<<<512, 256, 0, stream>>>(Qd, Kd, Vtd, Mb, ctx);
  out_gemm<<<dim3(8, 64), 256, 0, stream>>>(ctx, WoT, bo, (float*)d_out);
}

// Round 13
// 153.965 us; speedup vs baseline: 1.0419x; 1.0419x over previous
//
#include <hip/hip_runtime.h>

typedef __attribute__((ext_vector_type(8))) short s16x8;
typedef __attribute__((ext_vector_type(4))) float f32x4;
typedef __attribute__((ext_vector_type(16))) float f32x16;
typedef unsigned short u16;
typedef unsigned int u32;
typedef unsigned long long u64;

// ---------- helpers ----------
__device__ __forceinline__ u16 f2bf(float f) {            // RNE f32 -> bf16
  u32 u = __builtin_bit_cast(u32, f);
  u += 0x7fff + ((u >> 16) & 1);
  return (u16)(u >> 16);
}

__device__ __forceinline__ float exp2fast(float x) {
#if __has_builtin(__builtin_amdgcn_exp2f)
  return __builtin_amdgcn_exp2f(x);
#else
  return __expf(x * 0.6931471805599453f);
#endif
}

__device__ __forceinline__ void gload16(const void* g, void* l) {
  __builtin_amdgcn_global_load_lds((const __attribute__((address_space(1))) u32*)g,
                                   (__attribute__((address_space(3))) u32*)l, 16, 0, 0);
}

#define MFMA(a, b, c) __builtin_amdgcn_mfma_f32_16x16x32_bf16((a), (b), (c), 0, 0, 0)
#define MFMA32(a, b, c) __builtin_amdgcn_mfma_f32_32x32x16_bf16((a), (b), (c), 0, 0, 0)

// scale * log2(e), folded into Q at projection time
#define QSCALE 0.18033688011112042f

// ---------- fused prologue: cvt x3 | transpose x4 | mask bitpack (transposed) ----------
// roles by blockIdx.x range: [0,6144) cvt, [6144,10240) transpose, [10240,43008) mask
__global__ __launch_bounds__(256) void prep(
    const float* __restrict__ q, const float* __restrict__ k, const float* __restrict__ v,
    u16* __restrict__ oq, u16* __restrict__ ok, u16* __restrict__ ov,
    const float* __restrict__ W0, const float* __restrict__ W1,
    const float* __restrict__ W2, const float* __restrict__ W3,
    u16* __restrict__ T0, u16* __restrict__ T1, u16* __restrict__ T2, u16* __restrict__ T3,
    const int* __restrict__ mask, u64* __restrict__ mb) {
  __shared__ float t[32][33];
  const int bx = blockIdx.x, tid = threadIdx.x;
  if (bx < 6144) {                               // fp32 -> bf16, 8 elems/thread
    int z = bx >> 11;
    const float* src = (z == 0) ? q : (z == 1) ? k : v;
    u16* dst = (z == 0) ? oq : (z == 1) ? ok : ov;
    int i = (bx & 2047) * 256 + tid;
    const float4* s4 = (const float4*)src;
    float4 a = s4[2 * i], bb = s4[2 * i + 1];
    uint4 o;
    o.x = (u32)f2bf(a.x) | ((u32)f2bf(a.y) << 16);
    o.y = (u32)f2bf(a.z) | ((u32)f2bf(a.w) << 16);
    o.z = (u32)f2bf(bb.x) | ((u32)f2bf(bb.y) << 16);
    o.w = (u32)f2bf(bb.z) | ((u32)f2bf(bb.w) << 16);
    ((uint4*)dst)[i] = o;
  } else if (bx < 10240) {                       // W [1024][1024] f32 -> WT bf16
    int r = bx - 6144;
    int z = r >> 10, t2 = r & 1023;
    const float* W = (z == 0) ? W0 : (z == 1) ? W1 : (z == 2) ? W2 : W3;
    u16* WT = (z == 0) ? T0 : (z == 1) ? T1 : (z == 2) ? T2 : T3;
    int nb = t2 & 31, kb = t2 >> 5;
    int tx = tid & 31, ty = tid >> 5;
    int n = nb * 32 + tx;
#pragma unroll
    for (int j = 0; j < 4; j++) {
      int kk = kb * 32 + ty + 8 * j;
      t[ty + 8 * j][tx] = W[(size_t)kk * 1024 + n];
    }
    __syncthreads();
    int kk = kb * 32 + tx;
#pragma unroll
    for (int j = 0; j < 4; j++) {
      int n2 = nb * 32 + ty + 8 * j;
      WT[(size_t)n2 * 1024 + kk] = f2bf(t[tx][ty + 8 * j]);
    }
  } else {                                       // mask int32 [B,S,S] -> u64 [B][word][q]
    int wi = (bx - 10240) * 4 + (tid >> 6);
    int lane = tid & 63;
    u64 bits = __ballot(mask[((size_t)wi << 6) + lane] != 0);
    if (lane == 0) {
      int b_ = wi >> 16, q_ = (wi >> 5) & 2047, t_ = wi & 31;
      mb[((size_t)b_ << 16) + ((size_t)t_ << 11) + q_] = bits;   // transposed layout
    }
  }
}

// ---------- pipelined GEMM core (dist-2 dbuf, counted vmcnt, chunk swizzle) ----------
template <int BM, int BN>
__device__ __forceinline__ void gemm_core(const u16* __restrict__ A, const u16* __restrict__ BT,
                                          int m0, int n0, u16* Ash, u16* Bsh,
                                          f32x4 (&acc)[BM / 32][BN / 32]) {
  constexpr int MF = BM / 32, NF = BN / 32;
  constexpr int BATCH = BM / 32 + BN / 32;   // gload16 per thread per K-tile
  const int tid = threadIdx.x;
  const int lane = tid & 63, wid = tid >> 6;
  const int r16 = lane & 15, g = lane >> 4;
  const int wm = wid >> 1, wn = wid & 1;
  const int swz = r16 & 7;
  const f32x4 vz = {0.f, 0.f, 0.f, 0.f};
#pragma unroll
  for (int mf = 0; mf < MF; mf++)
#pragma unroll
    for (int nf = 0; nf < NF; nf++) acc[mf][nf] = vz;

  auto stage = [&](int buf, int k0) {
#pragma unroll
    for (int i = 0; i < MF; i++) {
      int ch = i * 256 + tid;
      int row = ch >> 3, sc = (ch & 7) ^ (row & 7);
      gload16(A + (((size_t)(m0 + row)) << 10) + k0 + sc * 8,
              Ash + (size_t)buf * (BM * 64) + ch * 8);
    }
#pragma unroll
    for (int i = 0; i < NF; i++) {
      int ch = i * 256 + tid;
      int row = ch >> 3, sc = (ch & 7) ^ (row & 7);
      gload16(BT + (((size_t)(n0 + row)) << 10) + k0 + sc * 8,
              Bsh + (size_t)buf * (BN * 64) + ch * 8);
    }
  };

  asm volatile("" ::: "memory");
  stage(0, 0);
  asm volatile("" ::: "memory");
  stage(1, 64);
  asm volatile("" ::: "memory");

  for (int t = 0; t < 16; t++) {
    const int cur = t & 1;
    if (t == 15) {
      asm volatile("s_waitcnt vmcnt(0)" ::: "memory");
    } else if constexpr (BATCH == 8) {
      asm volatile("s_waitcnt vmcnt(8)" ::: "memory");
    } else {
      asm volatile("s_waitcnt vmcnt(6)" ::: "memory");
    }
    asm volatile("s_barrier" ::: "memory");      // buf(cur) ready

    const u16* Acur = Ash + (size_t)cur * (BM * 64);
    const u16* Bcur = Bsh + (size_t)cur * (BN * 64);
    __builtin_amdgcn_s_setprio(1);
#pragma unroll
    for (int kk = 0; kk < 2; kk++) {
      const int c = (kk * 4 + g);
      s16x8 af[MF], bfr[NF];
#pragma unroll
      for (int mf = 0; mf < MF; mf++)
        af[mf] = *(const s16x8*)(Acur + ((wm * (BM / 2) + mf * 16 + r16) << 6) +
                                 ((c ^ swz) << 3));
#pragma unroll
      for (int nf = 0; nf < NF; nf++)
        bfr[nf] = *(const s16x8*)(Bcur + ((wn * (BN / 2) + nf * 16 + r16) << 6) +
                                  ((c ^ swz) << 3));
#pragma unroll
      for (int mf = 0; mf < MF; mf++)
#pragma unroll
        for (int nf = 0; nf < NF; nf++) acc[mf][nf] = MFMA(af[mf], bfr[nf], acc[mf][nf]);
    }
    __builtin_amdgcn_s_setprio(0);

    asm volatile("s_barrier" ::: "memory");      // all waves done reading buf(cur)
    if (t + 2 < 16) stage(cur, (t + 2) * 64);    // refill freed buffer
  }
}

// ---------- fused QKV projection: z=0 Q (pre-scaled), z=1 K, z=2 V (transposed) ----------
__global__ __launch_bounds__(256, 2) void proj_gemm(
    const u16* __restrict__ Xq, const u16* __restrict__ Xk, const u16* __restrict__ Xv,
    const u16* __restrict__ WqT, const u16* __restrict__ WkT, const u16* __restrict__ WvT,
    const float* __restrict__ bq, const float* __restrict__ bk, const float* __restrict__ bv,
    u16* __restrict__ Qo, u16* __restrict__ Ko, u16* __restrict__ Vto) {
  __shared__ u16 Ash[2 * 128 * 64], Bsh[2 * 128 * 64];
  const int z = blockIdx.z;
  const u16* A = (z == 0) ? Xq : (z == 1) ? Xk : Xv;
  const u16* BT = (z == 0) ? WqT : (z == 1) ? WkT : WvT;
  const float* bias = (z == 0) ? bq : (z == 1) ? bk : bv;
  u16* O = (z == 0) ? Qo : (z == 1) ? Ko : Vto;
  const float sc = (z == 0) ? QSCALE : 1.0f;
  const int m0 = blockIdx.y * 128, n0 = blockIdx.x * 128;
  f32x4 acc[4][4];
  gemm_core<128, 128>(A, BT, m0, n0, Ash, Bsh, acc);
  const int tid = threadIdx.x, lane = tid & 63, wid = tid >> 6;
  const int r16 = lane & 15, g = lane >> 4, wm = wid >> 1, wn = wid & 1;
#pragma unroll
  for (int nf = 0; nf < 4; nf++) {
    int col = n0 + wn * 64 + nf * 16 + r16;
    float bb = bias[col];
    int h = col >> 6, d = col & 63;
#pragma unroll
    for (int mf = 0; mf < 4; mf++) {
#pragma unroll
      for (int ri = 0; ri < 4; ri++) {
        int row = m0 + wm * 64 + mf * 16 + g * 4 + ri;
        int b_ = row >> 11, s_ = row & 2047;
        u16 val = f2bf((acc[mf][nf][ri] + bb) * sc);
        if (z < 2)
          O[((((size_t)b_ * 16 + h) * 2048 + s_) << 6) + d] = val;     // [B,H,S,64]
        else
          O[((((size_t)b_ * 16 + h) * 64 + d) << 11) + s_] = val;     // [B,H,64,S]
      }
    }
  }
}

// ---------- output projection (128x128 tile): out = ctx @ WoT^T + bo (fp32) ----------
__global__ __launch_bounds__(256, 2) void out_gemm(const u16* __restrict__ ctx,
                                                   const u16* __restrict__ WoT,
                                                   const float* __restrict__ bo,
                                                   float* __restrict__ out) {
  __shared__ u16 Ash[2 * 128 * 64], Bsh[2 * 128 * 64];
  const int m0 = blockIdx.y * 128, n0 = blockIdx.x * 128;
  f32x4 acc[4][4];
  gemm_core<128, 128>(ctx, WoT, m0, n0, Ash, Bsh, acc);
  const int tid = threadIdx.x, lane = tid & 63, wid = tid >> 6;
  const int r16 = lane & 15, g = lane >> 4, wm = wid >> 1, wn = wid & 1;
#pragma unroll
  for (int nf = 0; nf < 4; nf++) {
    int col = n0 + wn * 64 + nf * 16 + r16;
    float bb = bo[col];
#pragma unroll
    for (int mf = 0; mf < 4; mf++) {
#pragma unroll
      for (int ri = 0; ri < 4; ri++) {
        int row = m0 + wm * 64 + mf * 16 + g * 4 + ri;
        out[((size_t)row << 10) + col] = acc[mf][nf][ri] + bb;
      }
    }
  }
}

// ---------- softmax + in-register P->A-frag pack (32x32 C layout) ----------
__device__ __forceinline__ s16x8 pack4u(u32 a0, u32 a1, u32 b0, u32 b1) {
  union { u32 u[4]; s16x8 v; } p;
  p.u[0] = a0; p.u[1] = a1; p.u[2] = b0; p.u[3] = b1;
  return p.v;
}

__device__ __forceinline__ void softpack(const f32x16& sv, u32 wm, s16x8& pA, s16x8& pB) {
  float e[16];
#pragma unroll
  for (int qd = 0; qd < 4; qd++)
#pragma unroll
    for (int j = 0; j < 4; j++) {
      const int bit = qd * 8 + j;
      float ex = exp2fast(sv[qd * 4 + j]);
      u32 sext = (u32)(((int)(wm << (31 - bit))) >> 31);   // all-ones / zero
      e[qd * 4 + j] = __builtin_bit_cast(float, __builtin_bit_cast(u32, ex) & sext);
    }
#pragma unroll
  for (int n = 0; n < 2; n++) {
    u32 a0, a1, b0, b1;
    asm("v_cvt_pk_bf16_f32 %0, %1, %2" : "=v"(a0) : "v"(e[n * 8 + 0]), "v"(e[n * 8 + 1]));
    asm("v_cvt_pk_bf16_f32 %0, %1, %2" : "=v"(a1) : "v"(e[n * 8 + 2]), "v"(e[n * 8 + 3]));
    asm("v_cvt_pk_bf16_f32 %0, %1, %2" : "=v"(b0) : "v"(e[n * 8 + 4]), "v"(e[n * 8 + 5]));
    asm("v_cvt_pk_bf16_f32 %0, %1, %2" : "=v"(b1) : "v"(e[n * 8 + 6]), "v"(e[n * 8 + 7]));
    asm("v_permlane32_swap_b32 %0, %1" : "+v"(a0), "+v"(b0));
    asm("v_permlane32_swap_b32 %0, %1" : "+v"(a1), "+v"(b1));
    if (n == 0) pA = pack4u(a0, a1, b0, b1);
    else        pB = pack4u(a0, a1, b0, b1);
  }
}

// ---------- flash attention v11 (v9 + transposed coalesced mask loads) ----------
// block = 4 waves x 32 q = 128 q. 4 sub-buffers of 64 kv, dist-2 iterations,
// counted vmcnt(10), 2 barriers per 128 kv. Row-sum via ones-MFMA.
__global__ __launch_bounds__(256, 2) void flash_attn(const u16* __restrict__ Q,
                                                     const u16* __restrict__ K,
                                                     const u16* __restrict__ Vt,
                                                     const u64* __restrict__ Mb64,
                                                     u16* __restrict__ ctx) {
  __shared__ __align__(16) u16 Ksh[4][64][64];  // [sub-buf][kv][d]  chunk-swizzled
  __shared__ __align__(16) u16 Vsh[4][64][64];  // [sub-buf][d][kv]  chunk-swizzled

  const int tid = threadIdx.x, w = tid >> 6, lane = tid & 63;
  const int l31 = lane & 31, h5 = lane >> 5, l7 = lane & 7;

  // XCD-chunked swizzle: all 16 q-tiles of one (b,h) land on one XCD's L2
  int work = ((int)blockIdx.x & 7) * 64 + ((int)blockIdx.x >> 3);
  const int qt = work & 15, bh = work >> 4;     // bh = b*16+h
  const int b = bh >> 4, h = bh & 15;
  const int q0 = qt * 128 + w * 32;             // wave's 32 q rows

  const u16* Qb = Q + ((size_t)bh << 17);
  const u16* Kb = K + ((size_t)bh << 17);
  const u16* Vb = Vt + ((size_t)bh << 17);
  const u64* MrowT = Mb64 + ((size_t)b << 16) + (q0 + l31);  // transposed [b][word][q]

  const int srow = tid >> 3, sk16 = tid & 7;
#define STAGE(buf, kv0)                                                                   \
  {                                                                                       \
    _Pragma("unroll") for (int i = 0; i < 2; i++) {                                       \
      int row = i * 32 + srow;                                                            \
      int sc = sk16 ^ (row & 7);                                                          \
      gload16(Kb + (((size_t)((kv0) + row)) << 6) + sc * 8,                               \
              (char*)&Ksh[buf][0][0] + (i * 256 + tid) * 16);                             \
      gload16(Vb + (((size_t)row) << 11) + (kv0) + sc * 8,                                \
              (char*)&Vsh[buf][0][0] + (i * 256 + tid) * 16);                             \
    }                                                                                     \
  }

  // Q as B-fragment (pre-scaled): lane holds Q[q0+l31][dk*16 + h5*8 .. +7]
  s16x8 aq[4];
#pragma unroll
  for (int dk = 0; dk < 4; dk++)
    aq[dk] = *(const s16x8*)(Qb + ((q0 + l31) << 6) + dk * 16 + h5 * 8);
  asm volatile("" ::: "memory");   // pin: aq loads before batch0
  STAGE(0, 0);
  STAGE(1, 64);
  u64 m_c0 = MrowT[0], m_c1 = MrowT[(size_t)1 << 11];   // batch0: 8 gload + 2 mask
  asm volatile("" ::: "memory");
  STAGE(2, 128);
  STAGE(3, 192);
  u64 m_n0 = MrowT[(size_t)2 << 11], m_n1 = MrowT[(size_t)3 << 11];   // batch1
  asm volatile("" ::: "memory");

  s16x8 vones;
#pragma unroll
  for (int j = 0; j < 8; j++) vones[j] = (short)0x3F80;  // bf16 1.0

  f32x16 o0, o1, o4;
#pragma unroll
  for (int r = 0; r < 16; r++) { o0[r] = 0.f; o1[r] = 0.f; o4[r] = 0.f; }

  for (int t = 0; t < 16; t++) {            // 128 kv per iteration
    const int base = (t & 1) * 2;
    if (t == 15) {
      asm volatile("s_waitcnt vmcnt(0)" ::: "memory");
    } else {
      asm volatile("s_waitcnt vmcnt(10)" ::: "memory");
    }
    asm volatile("s_barrier" ::: "memory");          // sub-bufs base, base+1 ready

    const u16* KcA = &Ksh[base][0][0];
    const u16* KcB = &Ksh[base + 1][0][0];
    const u16* VcA = &Vsh[base][0][0];
    const u16* VcB = &Vsh[base + 1][0][0];

    // QK^T (32x32x16) for both 64-kv halves: 4 independent chains
    f32x16 s0, s1, s2, s3;
#pragma unroll
    for (int r = 0; r < 16; r++) { s0[r] = 0.f; s1[r] = 0.f; s2[r] = 0.f; s3[r] = 0.f; }
    __builtin_amdgcn_s_setprio(1);
#pragma unroll
    for (int dk = 0; dk < 4; dk++) {
      int ch = (((dk << 1) + h5) ^ l7) << 3;
      s16x8 akA0 = *(const s16x8*)(KcA + (l31 << 6) + ch);
      s16x8 akA1 = *(const s16x8*)(KcA + ((32 + l31) << 6) + ch);
      s16x8 akB0 = *(const s16x8*)(KcB + (l31 << 6) + ch);
      s16x8 akB1 = *(const s16x8*)(KcB + ((32 + l31) << 6) + ch);
      s0 = MFMA32(akA0, aq[dk], s0);
      s1 = MFMA32(akA1, aq[dk], s1);
      s2 = MFMA32(akB0, aq[dk], s2);
      s3 = MFMA32(akB1, aq[dk], s3);
    }
    __builtin_amdgcn_s_setprio(0);

    // half A: softmax+pack then PV (+ ones-MFMA row-sum)
    u64 mshA = m_c0 >> (h5 << 2);
    s16x8 pa[4];
    softpack(s0, (u32)mshA, pa[0], pa[1]);
    softpack(s1, (u32)(mshA >> 32), pa[2], pa[3]);
    __builtin_amdgcn_s_setprio(1);
#pragma unroll
    for (int km = 0; km < 4; km++) {
      int ch = (((km << 1) + h5) ^ l7) << 3;
      s16x8 bv0 = *(const s16x8*)(VcA + (l31 << 6) + ch);
      s16x8 bv1 = *(const s16x8*)(VcA + ((32 + l31) << 6) + ch);
      o0 = MFMA32(pa[km], bv0, o0);
      o1 = MFMA32(pa[km], bv1, o1);
      o4 = MFMA32(pa[km], vones, o4);
    }
    __builtin_amdgcn_s_setprio(0);

    // half B
    u64 mshB = m_c1 >> (h5 << 2);
    s16x8 pb[4];
    softpack(s2, (u32)mshB, pb[0], pb[1]);
    softpack(s3, (u32)(mshB >> 32), pb[2], pb[3]);
    __builtin_amdgcn_s_setprio(1);
#pragma unroll
    for (int km = 0; km < 4; km++) {
      int ch = (((km << 1) + h5) ^ l7) << 3;
      s16x8 bv0 = *(const s16x8*)(VcB + (l31 << 6) + ch);
      s16x8 bv1 = *(const s16x8*)(VcB + ((32 + l31) << 6) + ch);
      o0 = MFMA32(pb[km], bv0, o0);
      o1 = MFMA32(pb[km], bv1, o1);
      o4 = MFMA32(pb[km], vones, o4);
    }
    __builtin_amdgcn_s_setprio(0);

    asm volatile("s_barrier" ::: "memory");      // all waves done reading base, base+1
    u64 mw0 = 0, mw1 = 0;
    if (t + 2 < 16) {                            // restage freed sub-buffers (dist-2)
      STAGE(base, (2 * t + 4) * 64);
      STAGE(base + 1, (2 * t + 5) * 64);
      mw0 = MrowT[(size_t)(2 * t + 4) << 11];
      mw1 = MrowT[(size_t)(2 * t + 5) << 11];
    }
    m_c0 = m_n0; m_c1 = m_n1;
    m_n0 = mw0;  m_n1 = mw1;
  }
#undef STAGE

  // o4[r] = rowsum for q = q0 + (r&3)+8*(r>>2)+4*h5 -> normalize + write ctx bf16
#pragma unroll
  for (int r = 0; r < 16; r++) {
    int qr = (r & 3) + 8 * (r >> 2) + 4 * h5;
    size_t rowoff = ((size_t)((b << 11) + q0 + qr)) << 10;
    float iv = 1.f / o4[r];
    ctx[rowoff + (h << 6) + l31]      = f2bf(o0[r] * iv);
    ctx[rowoff + (h << 6) + 32 + l31] = f2bf(o1[r] * iv);
  }
}

// ---------- host ----------
extern "C" void kernel_launch(void* const* d_in, const int* in_sizes, int n_in,
                              void* d_out, int out_size, void* d_ws, size_t ws_size,
                              hipStream_t stream) {
  const float* query = (const float*)d_in[0];
  const float* key_  = (const float*)d_in[1];
  const float* value = (const float*)d_in[2];
  const int*   mask  = (const int*)d_in[3];
  const float* Wq = (const float*)d_in[4];
  const float* bq = (const float*)d_in[5];
  const float* Wk = (const float*)d_in[6];
  const float* bk = (const float*)d_in[7];
  const float* Wv = (const float*)d_in[8];
  const float* bv = (const float*)d_in[9];
  const float* Wo = (const float*)d_in[10];
  const float* bo = (const float*)d_in[11];

  const size_t MB = 1048576;
  char* ws = (char*)d_ws;
  u16* Xq  = (u16*)(ws + 0 * MB);
  u16* Xk  = (u16*)(ws + 8 * MB);
  u16* Xv  = (u16*)(ws + 16 * MB);
  u16* WqT = (u16*)(ws + 24 * MB);
  u16* WkT = (u16*)(ws + 26 * MB);
  u16* WvT = (u16*)(ws + 28 * MB);
  u16* WoT = (u16*)(ws + 30 * MB);
  u16* Qd  = (u16*)(ws + 32 * MB);
  u16* Kd  = (u16*)(ws + 40 * MB);
  u16* Vtd = (u16*)(ws + 48 * MB);
  u16* ctx = (u16*)(ws + 56 * MB);
  u64* Mb  = (u64*)(ws + 72 * MB);   // 1 MB bitmask (transposed [b][word][q])

  prep<<<43008, 256, 0, stream>>>(query, key_, value, Xq, Xk, Xv,
                                  Wq, Wk, Wv, Wo, WqT, WkT, WvT, WoT, mask, Mb);

  proj_gemm<<<dim3(8, 32, 3), 256, 0, stream>>>(Xq, Xk, Xv, WqT, WkT, WvT, bq, bk, bv,
                                                Qd, Kd, Vtd);
  flash_attn<<<512, 256, 0, stream>>>(Qd, Kd, Vtd, Mb, ctx);
  out_gemm<<<dim3(8, 32), 256, 0, stream>>>(ctx, WoT, bo, (float*)d_out);
}

// Round 14
// 141.206 us; speedup vs baseline: 1.1360x; 1.0904x over previous
//
#include <hip/hip_runtime.h>

typedef __attribute__((ext_vector_type(8))) short s16x8;
typedef __attribute__((ext_vector_type(4))) float f32x4;
typedef __attribute__((ext_vector_type(16))) float f32x16;
typedef unsigned short u16;
typedef unsigned int u32;
typedef unsigned long long u64;

// ---------- helpers ----------
__device__ __forceinline__ u16 f2bf(float f) {            // RNE f32 -> bf16
  u32 u = __builtin_bit_cast(u32, f);
  u += 0x7fff + ((u >> 16) & 1);
  return (u16)(u >> 16);
}

__device__ __forceinline__ float exp2fast(float x) {
#if __has_builtin(__builtin_amdgcn_exp2f)
  return __builtin_amdgcn_exp2f(x);
#else
  return __expf(x * 0.6931471805599453f);
#endif
}

__device__ __forceinline__ void gload16(const void* g, void* l) {
  __builtin_amdgcn_global_load_lds((const __attribute__((address_space(1))) u32*)g,
                                   (__attribute__((address_space(3))) u32*)l, 16, 0, 0);
}

#define MFMA(a, b, c) __builtin_amdgcn_mfma_f32_16x16x32_bf16((a), (b), (c), 0, 0, 0)
#define MFMA32(a, b, c) __builtin_amdgcn_mfma_f32_32x32x16_bf16((a), (b), (c), 0, 0, 0)

// scale * log2(e), folded into Q at projection time
#define QSCALE 0.18033688011112042f

// ---------- fused prologue: cvt x3 | transpose x4 | mask bitpack (transposed) ----------
// roles by blockIdx.x range: [0,6144) cvt, [6144,10240) transpose, [10240,43008) mask
__global__ __launch_bounds__(256) void prep(
    const float* __restrict__ q, const float* __restrict__ k, const float* __restrict__ v,
    u16* __restrict__ oq, u16* __restrict__ ok, u16* __restrict__ ov,
    const float* __restrict__ W0, const float* __restrict__ W1,
    const float* __restrict__ W2, const float* __restrict__ W3,
    u16* __restrict__ T0, u16* __restrict__ T1, u16* __restrict__ T2, u16* __restrict__ T3,
    const int* __restrict__ mask, u64* __restrict__ mb) {
  __shared__ float t[32][33];
  const int bx = blockIdx.x, tid = threadIdx.x;
  if (bx < 6144) {                               // fp32 -> bf16, 8 elems/thread
    int z = bx >> 11;
    const float* src = (z == 0) ? q : (z == 1) ? k : v;
    u16* dst = (z == 0) ? oq : (z == 1) ? ok : ov;
    int i = (bx & 2047) * 256 + tid;
    const float4* s4 = (const float4*)src;
    float4 a = s4[2 * i], bb = s4[2 * i + 1];
    uint4 o;
    o.x = (u32)f2bf(a.x) | ((u32)f2bf(a.y) << 16);
    o.y = (u32)f2bf(a.z) | ((u32)f2bf(a.w) << 16);
    o.z = (u32)f2bf(bb.x) | ((u32)f2bf(bb.y) << 16);
    o.w = (u32)f2bf(bb.z) | ((u32)f2bf(bb.w) << 16);
    ((uint4*)dst)[i] = o;
  } else if (bx < 10240) {                       // W [1024][1024] f32 -> WT bf16
    int r = bx - 6144;
    int z = r >> 10, t2 = r & 1023;
    const float* W = (z == 0) ? W0 : (z == 1) ? W1 : (z == 2) ? W2 : W3;
    u16* WT = (z == 0) ? T0 : (z == 1) ? T1 : (z == 2) ? T2 : T3;
    int nb = t2 & 31, kb = t2 >> 5;
    int tx = tid & 31, ty = tid >> 5;
    int n = nb * 32 + tx;
#pragma unroll
    for (int j = 0; j < 4; j++) {
      int kk = kb * 32 + ty + 8 * j;
      t[ty + 8 * j][tx] = W[(size_t)kk * 1024 + n];
    }
    __syncthreads();
    int kk = kb * 32 + tx;
#pragma unroll
    for (int j = 0; j < 4; j++) {
      int n2 = nb * 32 + ty + 8 * j;
      WT[(size_t)n2 * 1024 + kk] = f2bf(t[tx][ty + 8 * j]);
    }
  } else {                                       // mask int32 [B,S,S] -> u64 [B][word][q]
    int wi = (bx - 10240) * 4 + (tid >> 6);
    int lane = tid & 63;
    u64 bits = __ballot(mask[((size_t)wi << 6) + lane] != 0);
    if (lane == 0) {
      int b_ = wi >> 16, q_ = (wi >> 5) & 2047, t_ = wi & 31;
      mb[((size_t)b_ << 16) + ((size_t)t_ << 11) + q_] = bits;   // transposed layout
    }
  }
}

// ---------- pipelined GEMM core (dist-2 dbuf, counted vmcnt, chunk swizzle) ----------
template <int BM, int BN>
__device__ __forceinline__ void gemm_core(const u16* __restrict__ A, const u16* __restrict__ BT,
                                          int m0, int n0, u16* Ash, u16* Bsh,
                                          f32x4 (&acc)[BM / 32][BN / 32]) {
  constexpr int MF = BM / 32, NF = BN / 32;
  constexpr int BATCH = BM / 32 + BN / 32;   // gload16 per thread per K-tile
  const int tid = threadIdx.x;
  const int lane = tid & 63, wid = tid >> 6;
  const int r16 = lane & 15, g = lane >> 4;
  const int wm = wid >> 1, wn = wid & 1;
  const int swz = r16 & 7;
  const f32x4 vz = {0.f, 0.f, 0.f, 0.f};
#pragma unroll
  for (int mf = 0; mf < MF; mf++)
#pragma unroll
    for (int nf = 0; nf < NF; nf++) acc[mf][nf] = vz;

  auto stage = [&](int buf, int k0) {
#pragma unroll
    for (int i = 0; i < MF; i++) {
      int ch = i * 256 + tid;
      int row = ch >> 3, sc = (ch & 7) ^ (row & 7);
      gload16(A + (((size_t)(m0 + row)) << 10) + k0 + sc * 8,
              Ash + (size_t)buf * (BM * 64) + ch * 8);
    }
#pragma unroll
    for (int i = 0; i < NF; i++) {
      int ch = i * 256 + tid;
      int row = ch >> 3, sc = (ch & 7) ^ (row & 7);
      gload16(BT + (((size_t)(n0 + row)) << 10) + k0 + sc * 8,
              Bsh + (size_t)buf * (BN * 64) + ch * 8);
    }
  };

  asm volatile("" ::: "memory");
  stage(0, 0);
  asm volatile("" ::: "memory");
  stage(1, 64);
  asm volatile("" ::: "memory");

  for (int t = 0; t < 16; t++) {
    const int cur = t & 1;
    if (t == 15) {
      asm volatile("s_waitcnt vmcnt(0)" ::: "memory");
    } else if constexpr (BATCH == 8) {
      asm volatile("s_waitcnt vmcnt(8)" ::: "memory");
    } else {
      asm volatile("s_waitcnt vmcnt(6)" ::: "memory");
    }
    asm volatile("s_barrier" ::: "memory");      // buf(cur) ready

    const u16* Acur = Ash + (size_t)cur * (BM * 64);
    const u16* Bcur = Bsh + (size_t)cur * (BN * 64);
    __builtin_amdgcn_s_setprio(1);
#pragma unroll
    for (int kk = 0; kk < 2; kk++) {
      const int c = (kk * 4 + g);
      s16x8 af[MF], bfr[NF];
#pragma unroll
      for (int mf = 0; mf < MF; mf++)
        af[mf] = *(const s16x8*)(Acur + ((wm * (BM / 2) + mf * 16 + r16) << 6) +
                                 ((c ^ swz) << 3));
#pragma unroll
      for (int nf = 0; nf < NF; nf++)
        bfr[nf] = *(const s16x8*)(Bcur + ((wn * (BN / 2) + nf * 16 + r16) << 6) +
                                  ((c ^ swz) << 3));
#pragma unroll
      for (int mf = 0; mf < MF; mf++)
#pragma unroll
        for (int nf = 0; nf < NF; nf++) acc[mf][nf] = MFMA(af[mf], bfr[nf], acc[mf][nf]);
    }
    __builtin_amdgcn_s_setprio(0);

    asm volatile("s_barrier" ::: "memory");      // all waves done reading buf(cur)
    if (t + 2 < 16) stage(cur, (t + 2) * 64);    // refill freed buffer
  }
}

// ---------- fused QKV projection (64x128 tiles, XCD-chunked, 3 blocks/CU) ----------
// z=0 Q (pre-scaled), z=1 K, z=2 V (transposed)
__global__ __launch_bounds__(256, 3) void proj_gemm(
    const u16* __restrict__ Xq, const u16* __restrict__ Xk, const u16* __restrict__ Xv,
    const u16* __restrict__ WqT, const u16* __restrict__ WkT, const u16* __restrict__ WvT,
    const float* __restrict__ bq, const float* __restrict__ bk, const float* __restrict__ bv,
    u16* __restrict__ Qo, u16* __restrict__ Ko, u16* __restrict__ Vto) {
  __shared__ u16 Ash[2 * 64 * 64], Bsh[2 * 128 * 64];
  const int z = blockIdx.z;
  const u16* A = (z == 0) ? Xq : (z == 1) ? Xk : Xv;
  const u16* BT = (z == 0) ? WqT : (z == 1) ? WkT : WvT;
  const float* bias = (z == 0) ? bq : (z == 1) ? bk : bv;
  u16* O = (z == 0) ? Qo : (z == 1) ? Ko : Vto;
  const float sc = (z == 0) ? QSCALE : 1.0f;
  // XCD-chunked swizzle: per z, 512 blocks; XCD x gets works [64x,64x+64)
  // = 8 m-tiles x all 8 n-tiles -> A panels (1MB) + B (2MB) L2-resident.
  int lin = blockIdx.x + ((int)blockIdx.y << 3);
  int work = (lin & 7) * 64 + (lin >> 3);
  const int m0 = (work >> 3) * 64, n0 = (work & 7) * 128;
  f32x4 acc[2][4];
  gemm_core<64, 128>(A, BT, m0, n0, Ash, Bsh, acc);
  const int tid = threadIdx.x, lane = tid & 63, wid = tid >> 6;
  const int r16 = lane & 15, g = lane >> 4, wm = wid >> 1, wn = wid & 1;
#pragma unroll
  for (int nf = 0; nf < 4; nf++) {
    int col = n0 + wn * 64 + nf * 16 + r16;
    float bb = bias[col];
    int h = col >> 6, d = col & 63;
#pragma unroll
    for (int mf = 0; mf < 2; mf++) {
#pragma unroll
      for (int ri = 0; ri < 4; ri++) {
        int row = m0 + wm * 32 + mf * 16 + g * 4 + ri;
        int b_ = row >> 11, s_ = row & 2047;
        u16 val = f2bf((acc[mf][nf][ri] + bb) * sc);
        if (z < 2)
          O[((((size_t)b_ * 16 + h) * 2048 + s_) << 6) + d] = val;     // [B,H,S,64]
        else
          O[((((size_t)b_ * 16 + h) * 64 + d) << 11) + s_] = val;     // [B,H,64,S]
      }
    }
  }
}

// ---------- output projection (64x128 tiles, XCD-chunked): out = ctx @ WoT^T + bo ----------
__global__ __launch_bounds__(256, 3) void out_gemm(const u16* __restrict__ ctx,
                                                   const u16* __restrict__ WoT,
                                                   const float* __restrict__ bo,
                                                   float* __restrict__ out) {
  __shared__ u16 Ash[2 * 64 * 64], Bsh[2 * 128 * 64];
  int lin = blockIdx.x + ((int)blockIdx.y << 3);
  int work = (lin & 7) * 64 + (lin >> 3);
  const int m0 = (work >> 3) * 64, n0 = (work & 7) * 128;
  f32x4 acc[2][4];
  gemm_core<64, 128>(ctx, WoT, m0, n0, Ash, Bsh, acc);
  const int tid = threadIdx.x, lane = tid & 63, wid = tid >> 6;
  const int r16 = lane & 15, g = lane >> 4, wm = wid >> 1, wn = wid & 1;
#pragma unroll
  for (int nf = 0; nf < 4; nf++) {
    int col = n0 + wn * 64 + nf * 16 + r16;
    float bb = bo[col];
#pragma unroll
    for (int mf = 0; mf < 2; mf++) {
#pragma unroll
      for (int ri = 0; ri < 4; ri++) {
        int row = m0 + wm * 32 + mf * 16 + g * 4 + ri;
        out[((size_t)row << 10) + col] = acc[mf][nf][ri] + bb;
      }
    }
  }
}

// ---------- softmax + in-register P->A-frag pack (32x32 C layout) ----------
__device__ __forceinline__ s16x8 pack4u(u32 a0, u32 a1, u32 b0, u32 b1) {
  union { u32 u[4]; s16x8 v; } p;
  p.u[0] = a0; p.u[1] = a1; p.u[2] = b0; p.u[3] = b1;
  return p.v;
}

__device__ __forceinline__ void softpack(const f32x16& sv, u32 wm, s16x8& pA, s16x8& pB) {
  float e[16];
#pragma unroll
  for (int qd = 0; qd < 4; qd++)
#pragma unroll
    for (int j = 0; j < 4; j++) {
      const int bit = qd * 8 + j;
      float ex = exp2fast(sv[qd * 4 + j]);
      u32 sext = (u32)(((int)(wm << (31 - bit))) >> 31);   // all-ones / zero
      e[qd * 4 + j] = __builtin_bit_cast(float, __builtin_bit_cast(u32, ex) & sext);
    }
#pragma unroll
  for (int n = 0; n < 2; n++) {
    u32 a0, a1, b0, b1;
    asm("v_cvt_pk_bf16_f32 %0, %1, %2" : "=v"(a0) : "v"(e[n * 8 + 0]), "v"(e[n * 8 + 1]));
    asm("v_cvt_pk_bf16_f32 %0, %1, %2" : "=v"(a1) : "v"(e[n * 8 + 2]), "v"(e[n * 8 + 3]));
    asm("v_cvt_pk_bf16_f32 %0, %1, %2" : "=v"(b0) : "v"(e[n * 8 + 4]), "v"(e[n * 8 + 5]));
    asm("v_cvt_pk_bf16_f32 %0, %1, %2" : "=v"(b1) : "v"(e[n * 8 + 6]), "v"(e[n * 8 + 7]));
    asm("v_permlane32_swap_b32 %0, %1" : "+v"(a0), "+v"(b0));
    asm("v_permlane32_swap_b32 %0, %1" : "+v"(a1), "+v"(b1));
    if (n == 0) pA = pack4u(a0, a1, b0, b1);
    else        pB = pack4u(a0, a1, b0, b1);
  }
}

// ---------- flash attention v11 (v9 + transposed coalesced mask loads) ----------
// block = 4 waves x 32 q = 128 q. 4 sub-buffers of 64 kv, dist-2 iterations,
// counted vmcnt(10), 2 barriers per 128 kv. Row-sum via ones-MFMA.
__global__ __launch_bounds__(256, 2) void flash_attn(const u16* __restrict__ Q,
                                                     const u16* __restrict__ K,
                                                     const u16* __restrict__ Vt,
                                                     const u64* __restrict__ Mb64,
                                                     u16* __restrict__ ctx) {
  __shared__ __align__(16) u16 Ksh[4][64][64];  // [sub-buf][kv][d]  chunk-swizzled
  __shared__ __align__(16) u16 Vsh[4][64][64];  // [sub-buf][d][kv]  chunk-swizzled

  const int tid = threadIdx.x, w = tid >> 6, lane = tid & 63;
  const int l31 = lane & 31, h5 = lane >> 5, l7 = lane & 7;

  // XCD-chunked swizzle: all 16 q-tiles of one (b,h) land on one XCD's L2
  int work = ((int)blockIdx.x & 7) * 64 + ((int)blockIdx.x >> 3);
  const int qt = work & 15, bh = work >> 4;     // bh = b*16+h
  const int b = bh >> 4, h = bh & 15;
  const int q0 = qt * 128 + w * 32;             // wave's 32 q rows

  const u16* Qb = Q + ((size_t)bh << 17);
  const u16* Kb = K + ((size_t)bh << 17);
  const u16* Vb = Vt + ((size_t)bh << 17);
  const u64* MrowT = Mb64 + ((size_t)b << 16) + (q0 + l31);  // transposed [b][word][q]

  const int srow = tid >> 3, sk16 = tid & 7;
#define STAGE(buf, kv0)                                                                   \
  {                                                                                       \
    _Pragma("unroll") for (int i = 0; i < 2; i++) {                                       \
      int row = i * 32 + srow;                                                            \
      int sc = sk16 ^ (row & 7);                                                          \
      gload16(Kb + (((size_t)((kv0) + row)) << 6) + sc * 8,                               \
              (char*)&Ksh[buf][0][0] + (i * 256 + tid) * 16);                             \
      gload16(Vb + (((size_t)row) << 11) + (kv0) + sc * 8,                                \
              (char*)&Vsh[buf][0][0] + (i * 256 + tid) * 16);                             \
    }                                                                                     \
  }

  // Q as B-fragment (pre-scaled): lane holds Q[q0+l31][dk*16 + h5*8 .. +7]
  s16x8 aq[4];
#pragma unroll
  for (int dk = 0; dk < 4; dk++)
    aq[dk] = *(const s16x8*)(Qb + ((q0 + l31) << 6) + dk * 16 + h5 * 8);
  asm volatile("" ::: "memory");   // pin: aq loads before batch0
  STAGE(0, 0);
  STAGE(1, 64);
  u64 m_c0 = MrowT[0], m_c1 = MrowT[(size_t)1 << 11];   // batch0: 8 gload + 2 mask
  asm volatile("" ::: "memory");
  STAGE(2, 128);
  STAGE(3, 192);
  u64 m_n0 = MrowT[(size_t)2 << 11], m_n1 = MrowT[(size_t)3 << 11];   // batch1
  asm volatile("" ::: "memory");

  s16x8 vones;
#pragma unroll
  for (int j = 0; j < 8; j++) vones[j] = (short)0x3F80;  // bf16 1.0

  f32x16 o0, o1, o4;
#pragma unroll
  for (int r = 0; r < 16; r++) { o0[r] = 0.f; o1[r] = 0.f; o4[r] = 0.f; }

  for (int t = 0; t < 16; t++) {            // 128 kv per iteration
    const int base = (t & 1) * 2;
    if (t == 15) {
      asm volatile("s_waitcnt vmcnt(0)" ::: "memory");
    } else {
      asm volatile("s_waitcnt vmcnt(10)" ::: "memory");
    }
    asm volatile("s_barrier" ::: "memory");          // sub-bufs base, base+1 ready

    const u16* KcA = &Ksh[base][0][0];
    const u16* KcB = &Ksh[base + 1][0][0];
    const u16* VcA = &Vsh[base][0][0];
    const u16* VcB = &Vsh[base + 1][0][0];

    // QK^T (32x32x16) for both 64-kv halves: 4 independent chains
    f32x16 s0, s1, s2, s3;
#pragma unroll
    for (int r = 0; r < 16; r++) { s0[r] = 0.f; s1[r] = 0.f; s2[r] = 0.f; s3[r] = 0.f; }
    __builtin_amdgcn_s_setprio(1);
#pragma unroll
    for (int dk = 0; dk < 4; dk++) {
      int ch = (((dk << 1) + h5) ^ l7) << 3;
      s16x8 akA0 = *(const s16x8*)(KcA + (l31 << 6) + ch);
      s16x8 akA1 = *(const s16x8*)(KcA + ((32 + l31) << 6) + ch);
      s16x8 akB0 = *(const s16x8*)(KcB + (l31 << 6) + ch);
      s16x8 akB1 = *(const s16x8*)(KcB + ((32 + l31) << 6) + ch);
      s0 = MFMA32(akA0, aq[dk], s0);
      s1 = MFMA32(akA1, aq[dk], s1);
      s2 = MFMA32(akB0, aq[dk], s2);
      s3 = MFMA32(akB1, aq[dk], s3);
    }
    __builtin_amdgcn_s_setprio(0);

    // half A: softmax+pack then PV (+ ones-MFMA row-sum)
    u64 mshA = m_c0 >> (h5 << 2);
    s16x8 pa[4];
    softpack(s0, (u32)mshA, pa[0], pa[1]);
    softpack(s1, (u32)(mshA >> 32), pa[2], pa[3]);
    __builtin_amdgcn_s_setprio(1);
#pragma unroll
    for (int km = 0; km < 4; km++) {
      int ch = (((km << 1) + h5) ^ l7) << 3;
      s16x8 bv0 = *(const s16x8*)(VcA + (l31 << 6) + ch);
      s16x8 bv1 = *(const s16x8*)(VcA + ((32 + l31) << 6) + ch);
      o0 = MFMA32(pa[km], bv0, o0);
      o1 = MFMA32(pa[km], bv1, o1);
      o4 = MFMA32(pa[km], vones, o4);
    }
    __builtin_amdgcn_s_setprio(0);

    // half B
    u64 mshB = m_c1 >> (h5 << 2);
    s16x8 pb[4];
    softpack(s2, (u32)mshB, pb[0], pb[1]);
    softpack(s3, (u32)(mshB >> 32), pb[2], pb[3]);
    __builtin_amdgcn_s_setprio(1);
#pragma unroll
    for (int km = 0; km < 4; km++) {
      int ch = (((km << 1) + h5) ^ l7) << 3;
      s16x8 bv0 = *(const s16x8*)(VcB + (l31 << 6) + ch);
      s16x8 bv1 = *(const s16x8*)(VcB + ((32 + l31) << 6) + ch);
      o0 = MFMA32(pb[km], bv0, o0);
      o1 = MFMA32(pb[km], bv1, o1);
      o4 = MFMA32(pb[km], vones, o4);
    }
    __builtin_amdgcn_s_setprio(0);

    asm volatile("s_barrier" ::: "memory");      // all waves done reading base, base+1
    u64 mw0 = 0, mw1 = 0;
    if (t + 2 < 16) {                            // restage freed sub-buffers (dist-2)
      STAGE(base, (2 * t + 4) * 64);
      STAGE(base + 1, (2 * t + 5) * 64);
      mw0 = MrowT[(size_t)(2 * t + 4) << 11];
      mw1 = MrowT[(size_t)(2 * t + 5) << 11];
    }
    m_c0 = m_n0; m_c1 = m_n1;
    m_n0 = mw0;  m_n1 = mw1;
  }
#undef STAGE

  // o4[r] = rowsum for q = q0 + (r&3)+8*(r>>2)+4*h5 -> normalize + write ctx bf16
#pragma unroll
  for (int r = 0; r < 16; r++) {
    int qr = (r & 3) + 8 * (r >> 2) + 4 * h5;
    size_t rowoff = ((size_t)((b << 11) + q0 + qr)) << 10;
    float iv = 1.f / o4[r];
    ctx[rowoff + (h << 6) + l31]      = f2bf(o0[r] * iv);
    ctx[rowoff + (h << 6) + 32 + l31] = f2bf(o1[r] * iv);
  }
}

// ---------- host ----------
extern "C" void kernel_launch(void* const* d_in, const int* in_sizes, int n_in,
                              void* d_out, int out_size, void* d_ws, size_t ws_size,
                              hipStream_t stream) {
  const float* query = (const float*)d_in[0];
  const float* key_  = (const float*)d_in[1];
  const float* value = (const float*)d_in[2];
  const int*   mask  = (const int*)d_in[3];
  const float* Wq = (const float*)d_in[4];
  const float* bq = (const float*)d_in[5];
  const float* Wk = (const float*)d_in[6];
  const float* bk = (const float*)d_in[7];
  const float* Wv = (const float*)d_in[8];
  const float* bv = (const float*)d_in[9];
  const float* Wo = (const float*)d_in[10];
  const float* bo = (const float*)d_in[11];

  const size_t MB = 1048576;
  char* ws = (char*)d_ws;
  u16* Xq  = (u16*)(ws + 0 * MB);
  u16* Xk  = (u16*)(ws + 8 * MB);
  u16* Xv  = (u16*)(ws + 16 * MB);
  u16* WqT = (u16*)(ws + 24 * MB);
  u16* WkT = (u16*)(ws + 26 * MB);
  u16* WvT = (u16*)(ws + 28 * MB);
  u16* WoT = (u16*)(ws + 30 * MB);
  u16* Qd  = (u16*)(ws + 32 * MB);
  u16* Kd  = (u16*)(ws + 40 * MB);
  u16* Vtd = (u16*)(ws + 48 * MB);
  u16* ctx = (u16*)(ws + 56 * MB);
  u64* Mb  = (u64*)(ws + 72 * MB);   // 1 MB bitmask (transposed [b][word][q])

  prep<<<43008, 256, 0, stream>>>(query, key_, value, Xq, Xk, Xv,
                                  Wq, Wk, Wv, Wo, WqT, WkT, WvT, WoT, mask, Mb);

  proj_gemm<<<dim3(8, 64, 3), 256, 0, stream>>>(Xq, Xk, Xv, WqT, WkT, WvT, bq, bk, bv,
                                                Qd, Kd, Vtd);
  flash_attn<<<512, 256, 0, stream>>>(Qd, Kd, Vtd, Mb, ctx);
  out_gemm<<<dim3(8, 64), 256, 0, stream>>>(ctx, WoT, bo, (float*)d_out);
}